// Round 19
// baseline (90185.822 us; speedup 1.0000x reference)
//
#include <hip/hip_runtime.h>
#include <math.h>

#define T_DEC 256
#define NKA 56          // A: K=1792 = 56 k-chunks of 32
#define NKD 80          // D: K=2560 = 80 k-chunks of 32
#define NBLK 512
#define AGS __HIP_MEMORY_SCOPE_AGENT

typedef __attribute__((ext_vector_type(8))) short bf16x8;
typedef __attribute__((ext_vector_type(4))) float f32x4;

__device__ __forceinline__ float sigf(float x) { return 1.0f / (1.0f + expf(-x)); }
__device__ __forceinline__ unsigned short f2u(float f) {   // RNE bf16
    union { float ff; unsigned int i; } v; v.ff = f;
    unsigned int x = v.i;
    return (unsigned short)((x + 0x7FFFu + ((x >> 16) & 1u)) >> 16);
}
// offset of X[b][k] inside a B-frag-ordered X buffer (chunks of 32 k, 2 col-tiles)
__device__ __forceinline__ size_t xoff(int k, int b) {
    int c = k >> 5, kk = k & 31, ct = b >> 4;
    int lane = (b & 15) | ((kk >> 3) << 4);
    int j = kk & 7;
    return ((size_t)(c * 2 + ct) * 64 + lane) * 8 + j;
}

// ---------------- relaxed-poll hierarchical grid barrier ----------------
// R13 post-mortem: ACQUIRE-per-poll invalidates caches continuously (0.94%
// VALUBusy). Fix: RELAXED polls (coherent-point loads, no inv) + ONE
// __threadfence per block per barrier (release before arrival, acquire after).
struct GBar {
    unsigned int gcnt[8][32];   // one 128B line per XCD-group counter
    unsigned int gep[8][32];
    unsigned int rcnt[32];
    unsigned int rep[32];
};

__device__ __forceinline__ void gbar(GBar* B) {
    __syncthreads();
    if (threadIdx.x == 0) {
        __threadfence();                       // release my writes
        int grp = blockIdx.x & 7;
        unsigned e = __hip_atomic_load(&B->gep[grp][0], __ATOMIC_RELAXED, AGS);
        unsigned old = __hip_atomic_fetch_add(&B->gcnt[grp][0], 1u, __ATOMIC_RELAXED, AGS);
        if (old == (NBLK / 8) - 1) {
            __hip_atomic_store(&B->gcnt[grp][0], 0u, __ATOMIC_RELAXED, AGS);
            unsigned re = __hip_atomic_load(&B->rep[0], __ATOMIC_RELAXED, AGS);
            unsigned rold = __hip_atomic_fetch_add(&B->rcnt[0], 1u, __ATOMIC_RELAXED, AGS);
            if (rold == 7u) {
                __hip_atomic_store(&B->rcnt[0], 0u, __ATOMIC_RELAXED, AGS);
                __hip_atomic_store(&B->rep[0], re + 1u, __ATOMIC_RELAXED, AGS);
            } else {
                while (__hip_atomic_load(&B->rep[0], __ATOMIC_RELAXED, AGS) == re)
                    __builtin_amdgcn_s_sleep(4);
            }
            __hip_atomic_store(&B->gep[grp][0], e + 1u, __ATOMIC_RELAXED, AGS);
        } else {
            while (__hip_atomic_load(&B->gep[grp][0], __ATOMIC_RELAXED, AGS) == e)
                __builtin_amdgcn_s_sleep(8);
        }
        __threadfence();                       // acquire others' writes
    }
    __syncthreads();
}

// ---------------- parameter block ----------------
struct P {
    const unsigned short *slabA, *slabD;
    unsigned short *XAb0, *XAb1, *XDb0, *XDb1;
    const float *bA, *bD;
    float *hA0, *hA1, *cA, *hD0, *hD1, *cD;
    const float *enc, *pm, *wqT, *Wlc, *Wld, *vatt;
    const float *Wp, *bp, *Wg, *bg;
    const float *inputs, *Wpre1, *Wpre2;
    float *aw, *cum, *ctx0, *ctx1;
    const int* mlen;
    float *mel, *gate, *align;
    GBar* bar;
};

// ---------------- shared memory union ----------------
struct SHg { f32x4 red[3][2][64]; };
struct SHa {
    float wlc0[31][32], wlc1[31][32];
    float wlds[128][36];
    float vs[128];
    float hs[1024];
    float red[256];
    float pqs[128];
    float aw0s[288], aw1s[288];
    float sm[256];
    float red4[4];
};
struct SHp { float hc[1536]; float redp[164]; };
struct SHn { float xs[80]; float h1[256]; };
union SHU { SHg g; SHa a; SHp p; SHn n; };

// ---------------- small prologue kernels ----------------
__global__ void convert_mlen(const void* p, int* out) {
    int b = threadIdx.x;
    const int* pi = (const int*)p;
    const float* pf = (const float*)p;
    __shared__ int mode;
    if (b == 0) {
        int i0 = pi[0], i1 = pi[1];
        float f0 = pf[0];
        if (i0 >= 1 && i0 <= 512 && i1 == 0) mode = 2;
        else if (i0 >= 1 && i0 <= 512) mode = 0;
        else if (f0 >= 1.0f && f0 <= 512.0f) mode = 1;
        else mode = 0;
    }
    __syncthreads();
    int v;
    if (mode == 2)      v = pi[2 * b];
    else if (mode == 1) v = (int)(pf[b] + 0.5f);
    else                v = pi[b];
    if (v < 1) v = 1;
    if (v > 256) v = 256;
    out[b] = v;
}

__global__ void zero_f(float* __restrict__ p, int n) {
    int i = blockIdx.x * blockDim.x + threadIdx.x;
    if (i < n) p[i] = 0.0f;
}

__global__ __launch_bounds__(128) void proc_mem(const float* __restrict__ mem,
                                                const float* __restrict__ Wm,
                                                float* __restrict__ pm) {
    int r = blockIdx.x;
    int d = threadIdx.x;
    __shared__ float xs[512];
    for (int k = d; k < 512; k += 128) xs[k] = mem[(size_t)r * 512 + k];
    __syncthreads();
    const float* wr = Wm + (size_t)d * 512;
    float s = 0.f;
    for (int k = 0; k < 512; k += 4) {
        float4 w = *reinterpret_cast<const float4*>(wr + k);
        s = fmaf(xs[k], w.x, s); s = fmaf(xs[k+1], w.y, s);
        s = fmaf(xs[k+2], w.z, s); s = fmaf(xs[k+3], w.w, s);
    }
    pm[(size_t)r * 128 + d] = s;
}

__global__ __launch_bounds__(256) void transpose_wq(const float* __restrict__ Wq,
                                                    float* __restrict__ wqT) {
    int i = blockIdx.x * 256 + threadIdx.x;
    int d = i & 127, k = i >> 7;
    wqT[i] = Wq[(size_t)d * 1024 + k];
}

// repack W into A-fragment lane order (verified R17/R18)
__global__ __launch_bounds__(256) void repack_mfma(const float* __restrict__ Wih,
                                                   const float* __restrict__ Whh,
                                                   unsigned short* __restrict__ slab,
                                                   int KIH, int nK, long total) {
    long idx = (long)blockIdx.x * 256 + threadIdx.x;
    if (idx >= total) return;
    int j = (int)(idx & 7);
    int l = (int)((idx >> 3) & 63);
    long rest = idx >> 9;
    int i = (int)(rest % nK), rt = (int)(rest / nK);
    int x = l & 15;
    int row = (x & 3) * 1024 + rt * 4 + (x >> 2);
    int k = i * 32 + (l >> 4) * 8 + j;
    float v = (k < KIH) ? Wih[(size_t)row * KIH + k]
                        : Whh[(size_t)row * 1024 + (k - KIH)];
    slab[idx] = f2u(v);
}

// ---------------- phase1: MFMA z-GEMMs + fused gates ----------------
template<int NQ>
__device__ __forceinline__ void mfma_part(const unsigned short* __restrict__ ap,
                                          const unsigned short* __restrict__ xp,
                                          f32x4& acc0, f32x4& acc1) {
    bf16x8 ab[6], bb0[6], bb1[6];
    #pragma unroll
    for (int p = 0; p < 6; ++p) {
        ab[p]  = *reinterpret_cast<const bf16x8*>(ap + (size_t)p * 512);
        bb0[p] = *reinterpret_cast<const bf16x8*>(xp + (size_t)(2 * p) * 512);
        bb1[p] = *reinterpret_cast<const bf16x8*>(xp + (size_t)(2 * p + 1) * 512);
    }
    #pragma unroll
    for (int i = 0; i < NQ; ++i) {
        const int s = i % 6;
        acc0 = __builtin_amdgcn_mfma_f32_16x16x32_bf16(ab[s], bb0[s], acc0, 0, 0, 0);
        acc1 = __builtin_amdgcn_mfma_f32_16x16x32_bf16(ab[s], bb1[s], acc1, 0, 0, 0);
        if (i + 6 < NQ) {
            ab[s]  = *reinterpret_cast<const bf16x8*>(ap + (size_t)(i + 6) * 512);
            bb0[s] = *reinterpret_cast<const bf16x8*>(xp + (size_t)(2 * (i + 6)) * 512);
            bb1[s] = *reinterpret_cast<const bf16x8*>(xp + (size_t)(2 * (i + 6) + 1) * 512);
        }
    }
}

__device__ void phase1(const P& p, SHU* sh, int t) {
    int blk = blockIdx.x;
    bool isA = blk < 256;
    if (isA ? (t >= 255) : (t < 0)) return;
    int pc = t & 1, pn = (t + 1) & 1;
    const unsigned short* XA = pc ? p.XAb1 : p.XAb0;
    const unsigned short* XD = pc ? p.XDb1 : p.XDb0;
    unsigned short* XAn = pn ? p.XAb1 : p.XAb0;
    unsigned short* XDn = pn ? p.XDb1 : p.XDb0;
    float* hAn = pn ? p.hA1 : p.hA0;
    float* hDn = pc ? p.hD1 : p.hD0;
    int rt = isA ? blk : blk - 256;
    int tid = threadIdx.x;
    int l = tid & 63, w = tid >> 6;
    f32x4 acc0 = {0.f, 0.f, 0.f, 0.f}, acc1 = {0.f, 0.f, 0.f, 0.f};
    if (isA) {
        const unsigned short* ap = p.slabA + ((size_t)(rt * NKA + w * 14) * 64 + l) * 8;
        const unsigned short* xp = XA + ((size_t)(w * 14) * 128 + l) * 8;
        mfma_part<14>(ap, xp, acc0, acc1);
    } else {
        const unsigned short* ap = p.slabD + ((size_t)(rt * NKD + w * 20) * 64 + l) * 8;
        const unsigned short* xp = XD + ((size_t)(w * 20) * 128 + l) * 8;
        mfma_part<20>(ap, xp, acc0, acc1);
    }
    if (w > 0) { sh->g.red[w - 1][0][l] = acc0; sh->g.red[w - 1][1][l] = acc1; }
    __syncthreads();
    if (w != 0) return;
    #pragma unroll
    for (int q = 0; q < 3; ++q) {
        f32x4 r0 = sh->g.red[q][0][l], r1 = sh->g.red[q][1][l];
        acc0[0] += r0[0]; acc0[1] += r0[1]; acc0[2] += r0[2]; acc0[3] += r0[3];
        acc1[0] += r1[0]; acc1[1] += r1[1]; acc1[2] += r1[2]; acc1[3] += r1[3];
    }
    int u = rt * 4 + (l >> 4);
    const float* bias = isA ? p.bA : p.bD;
    float bi = bias[u], bf = bias[1024 + u], bg = bias[2048 + u], bo = bias[3072 + u];
    float* cio = isA ? p.cA : p.cD;
    float* hout = isA ? hAn : hDn;
    #pragma unroll
    for (int ct = 0; ct < 2; ++ct) {
        f32x4 z = ct ? acc1 : acc0;
        int b = ct * 16 + (l & 15);
        int idx = b * 1024 + u;
        float cn = sigf(z[1] + bf) * cio[idx] + sigf(z[0] + bi) * tanhf(z[2] + bg);
        float hn = sigf(z[3] + bo) * tanhf(cn);
        cio[idx] = cn;
        hout[idx] = hn;
        unsigned short hb = f2u(hn);
        if (isA) {
            XAn[xoff(768 + u, b)] = hb;
            XDn[xoff(u, b)] = hb;
        } else {
            XDn[xoff(1536 + u, b)] = hb;
        }
    }
}

// ---------------- phase2: proj(t) | attn(t+1)+ctx | prenet(t+2) ------------
__device__ void phase2(const P& p, SHU* shp, int t) {
    SHU& sh = *shp;
    const int tid = threadIdx.x;
    const int blk = blockIdx.x;
    int pc = t & 1, pn = (t + 1) & 1;
    const float* ctxc = pc ? p.ctx1 : p.ctx0;
    float* ctxn = pn ? p.ctx1 : p.ctx0;
    const float* hAnext = pn ? p.hA1 : p.hA0;
    const float* hDcur  = pc ? p.hD1 : p.hD0;
    unsigned short* XAn = pn ? p.XAb1 : p.XAb0;
    unsigned short* XDn = pn ? p.XDb1 : p.XDb0;
    if (blk < 32) {
        if (t < 0) return;
        int b = blk;
        for (int k = tid; k < 1024; k += 256) sh.p.hc[k] = hDcur[(size_t)b * 1024 + k];
        for (int k = tid; k < 512; k += 256)  sh.p.hc[1024 + k] = ctxc[(size_t)b * 512 + k];
        __syncthreads();
        if (tid < 162) {
            int o = tid >> 1, hf = tid & 1;
            const float* wr = (o < 80) ? (p.Wp + (size_t)o * 1536) : p.Wg;
            float s = 0.f;
            int k0 = hf * 768;
            for (int k = k0; k < k0 + 768; k += 4) {
                float4 w = *reinterpret_cast<const float4*>(wr + k);
                s = fmaf(sh.p.hc[k], w.x, s);   s = fmaf(sh.p.hc[k+1], w.y, s);
                s = fmaf(sh.p.hc[k+2], w.z, s); s = fmaf(sh.p.hc[k+3], w.w, s);
            }
            sh.p.redp[tid] = s;
        }
        __syncthreads();
        if (tid < 81) {
            float s = sh.p.redp[2 * tid] + sh.p.redp[2 * tid + 1];
            if (tid < 80) p.mel[((size_t)b * T_DEC + t) * 80 + tid] = s + p.bp[tid];
            else          p.gate[(size_t)b * T_DEC + t] = s + p.bg[0];
        }
    } else if (blk < 64) {
        if (t < -1 || t >= 255) return;
        int b = blk - 32, tt = t + 1;
        for (int i = tid; i < 992; i += 256) {
            int k = i >> 5, f = i & 31;
            sh.a.wlc0[k][f] = p.Wlc[(size_t)f * 62 + k];
            sh.a.wlc1[k][f] = p.Wlc[(size_t)f * 62 + 31 + k];
        }
        for (int i = tid; i < 4096; i += 256) sh.a.wlds[i >> 5][i & 31] = p.Wld[i];
        if (tid < 128) sh.a.vs[tid] = p.vatt[tid];
        for (int k = tid; k < 1024; k += 256) sh.a.hs[k] = hAnext[(size_t)b * 1024 + k];
        for (int i = tid; i < 288; i += 256) {
            int pos = i - 16;
            float v0 = 0.f, v1 = 0.f;
            if (pos >= 0 && pos < 256) {
                v0 = p.aw[(size_t)b * 256 + pos];
                v1 = p.cum[(size_t)b * 256 + pos];
            }
            sh.a.aw0s[i] = v0; sh.a.aw1s[i] = v1;
        }
        __syncthreads();
        {
            int d = tid & 127, hf = tid >> 7;
            float s = 0.f;
            int k0 = hf * 512;
            for (int k = k0; k < k0 + 512; ++k)
                s = fmaf(sh.a.hs[k], p.wqT[(size_t)k * 128 + d], s);
            sh.a.red[tid] = s;
        }
        __syncthreads();
        if (tid < 128) sh.a.pqs[tid] = sh.a.red[tid] + sh.a.red[tid + 128];
        __syncthreads();
        float cf[32];
        #pragma unroll
        for (int f = 0; f < 32; ++f) cf[f] = 0.f;
        for (int k = 0; k < 31; ++k) {
            float a0 = sh.a.aw0s[tid + 1 + k], a1 = sh.a.aw1s[tid + 1 + k];
            #pragma unroll
            for (int fq = 0; fq < 8; ++fq) {
                float4 w0 = *reinterpret_cast<const float4*>(&sh.a.wlc0[k][fq << 2]);
                float4 w1 = *reinterpret_cast<const float4*>(&sh.a.wlc1[k][fq << 2]);
                cf[fq*4+0] = fmaf(a0, w0.x, fmaf(a1, w1.x, cf[fq*4+0]));
                cf[fq*4+1] = fmaf(a0, w0.y, fmaf(a1, w1.y, cf[fq*4+1]));
                cf[fq*4+2] = fmaf(a0, w0.z, fmaf(a1, w1.z, cf[fq*4+2]));
                cf[fq*4+3] = fmaf(a0, w0.w, fmaf(a1, w1.w, cf[fq*4+3]));
            }
        }
        float e = 0.f;
        {
            const float* pmr = p.pm + ((size_t)b * 256 + tid) * 128;
            for (int d = 0; d < 128; ++d) {
                float loc = 0.f;
                #pragma unroll
                for (int fq = 0; fq < 8; ++fq) {
                    float4 w = *reinterpret_cast<const float4*>(&sh.a.wlds[d][fq << 2]);
                    loc = fmaf(cf[fq*4+0], w.x, loc); loc = fmaf(cf[fq*4+1], w.y, loc);
                    loc = fmaf(cf[fq*4+2], w.z, loc); loc = fmaf(cf[fq*4+3], w.w, loc);
                }
                float a = tanhf(sh.a.pqs[d] + loc + pmr[d]);
                e = fmaf(a, sh.a.vs[d], e);
            }
        }
        if (tid >= p.mlen[b]) e = -1e9f;
        float m = e;
        #pragma unroll
        for (int o2 = 32; o2 >= 1; o2 >>= 1) m = fmaxf(m, __shfl_xor(m, o2));
        if ((tid & 63) == 0) sh.a.red4[tid >> 6] = m;
        __syncthreads();
        m = fmaxf(fmaxf(sh.a.red4[0], sh.a.red4[1]), fmaxf(sh.a.red4[2], sh.a.red4[3]));
        __syncthreads();
        float pe = expf(e - m);
        float s = pe;
        #pragma unroll
        for (int o2 = 32; o2 >= 1; o2 >>= 1) s += __shfl_xor(s, o2);
        if ((tid & 63) == 0) sh.a.red4[tid >> 6] = s;
        __syncthreads();
        s = sh.a.red4[0] + sh.a.red4[1] + sh.a.red4[2] + sh.a.red4[3];
        float w = pe / s;
        sh.a.sm[tid] = w;
        p.aw[(size_t)b * 256 + tid] = w;
        p.cum[(size_t)b * 256 + tid] += w;
        p.align[((size_t)b * T_DEC + tt) * 256 + tid] = w;
        __syncthreads();
        for (int d = tid; d < 512; d += 256) {
            const float* mb = p.enc + (size_t)b * 131072 + d;
            float s2 = 0.f;
            for (int q2 = 0; q2 < 256; ++q2) s2 = fmaf(sh.a.sm[q2], mb[(size_t)q2 * 512], s2);
            ctxn[(size_t)b * 512 + d] = s2;
            unsigned short cb16 = f2u(s2);
            XAn[xoff(256 + d, b)] = cb16;
            XDn[xoff(1024 + d, b)] = cb16;
        }
    } else if (blk < 96) {
        int ts = t + 2;
        if (ts > 255) return;
        int b = blk - 64;
        if (tid < 80) sh.n.xs[tid] = (ts == 0) ? 0.0f
                        : p.inputs[((size_t)b * T_DEC + (ts - 1)) * 80 + tid];
        __syncthreads();
        {
            const float* wr = p.Wpre1 + (size_t)tid * 80;
            float s = 0.f;
            #pragma unroll 8
            for (int k = 0; k < 80; ++k) s = fmaf(sh.n.xs[k], wr[k], s);
            sh.n.h1[tid] = fmaxf(s, 0.0f);
        }
        __syncthreads();
        {
            const float* wr = p.Wpre2 + (size_t)tid * 256;
            float s = 0.f;
            for (int k = 0; k < 256; k += 4) {
                float4 w = *reinterpret_cast<const float4*>(wr + k);
                s = fmaf(sh.n.h1[k], w.x, s);   s = fmaf(sh.n.h1[k+1], w.y, s);
                s = fmaf(sh.n.h1[k+2], w.z, s); s = fmaf(sh.n.h1[k+3], w.w, s);
            }
            XAn[xoff(tid, b)] = f2u(fmaxf(s, 0.0f));
        }
    }
}

// ---------------- persistent kernel (custom relaxed barrier) ----------------
__global__ __launch_bounds__(256, 4) void coop_main(P p) {
    __shared__ SHU sh;
    phase2(p, &sh, -2);            // prenet(0)
    gbar(p.bar);
    for (int t = -1; t <= 255; ++t) {
        phase1(p, &sh, t);
        gbar(p.bar);
        phase2(p, &sh, t);
        gbar(p.bar);
    }
}

// ---------------- discrete fallback ----------------
__global__ __launch_bounds__(256) void fb1(P p, int t) { __shared__ SHU sh; phase1(p, &sh, t); }
__global__ __launch_bounds__(256) void fb2(P p, int t) { __shared__ SHU sh; phase2(p, &sh, t); }

// ---------------- host ----------------
extern "C" void kernel_launch(void* const* d_in, const int* in_sizes, int n_in,
                              void* d_out, int out_size, void* d_ws, size_t ws_size,
                              hipStream_t stream) {
    const float* enc    = (const float*)d_in[0];
    const float* inputs = (const float*)d_in[1];
    const void*  mlraw  = d_in[2];
    const float* W_pre1 = (const float*)d_in[3];
    const float* W_pre2 = (const float*)d_in[4];
    const float* Wih_a  = (const float*)d_in[5];
    const float* Whh_a  = (const float*)d_in[6];
    const float* b_a    = (const float*)d_in[7];
    const float* W_q    = (const float*)d_in[8];
    const float* W_mem  = (const float*)d_in[9];
    const float* Wlc    = (const float*)d_in[10];
    const float* Wld    = (const float*)d_in[11];
    const float* v_att  = (const float*)d_in[12];
    const float* Wih_d  = (const float*)d_in[13];
    const float* Whh_d  = (const float*)d_in[14];
    const float* b_d    = (const float*)d_in[15];
    const float* W_proj = (const float*)d_in[16];
    const float* b_proj = (const float*)d_in[17];
    const float* W_gate = (const float*)d_in[18];
    const float* b_gate = (const float*)d_in[19];

    const long SLAB_A = (long)256 * NKA * 512;    // 7,340,032 ushorts
    const long SLAB_D = (long)256 * NKD * 512;    // 10,485,760 ushorts
    const long XA_SZ  = (long)NKA * 2 * 512;      // 57,344 ushorts
    const long XD_SZ  = (long)NKD * 2 * 512;      // 81,920 ushorts

    float* ws = (float*)d_ws;
    size_t o = 0;
    float* pm  = ws + o; o += 1048576;
    float* wqT = ws + o; o += 131072;
    size_t zs0 = o;
    float* hA0 = ws + o; o += 32768;
    float* hA1 = ws + o; o += 32768;
    float* cA  = ws + o; o += 32768;
    float* hD0 = ws + o; o += 32768;
    float* hD1 = ws + o; o += 32768;
    float* cD  = ws + o; o += 32768;
    float* aw  = ws + o; o += 8192;
    float* cum = ws + o; o += 8192;
    float* ctx0 = ws + o; o += 16384;
    float* ctx1 = ws + o; o += 16384;
    unsigned short* XAb0 = (unsigned short*)(ws + o);
    o += (size_t)(2 * XA_SZ + 2 * XD_SZ + 1) / 2;   // 139,264 floats
    GBar* bar = (GBar*)(ws + o); o += 576;
    int zlen = (int)(o - zs0);
    int* mlen = (int*)(ws + o); o += 32;
    size_t small_fl = o;
    unsigned short* slabA = (unsigned short*)(ws + o);
    unsigned short* slabD = slabA + SLAB_A;
    size_t full_fl = o + (size_t)(SLAB_A + SLAB_D + 1) / 2;
    (void)small_fl;
    if (ws_size < full_fl * 4) return;   // diagnostic: 0.1455 signature

    float* out       = (float*)d_out;
    float* mel_out   = out;
    float* gate_out  = out + (size_t)32 * 256 * 80;
    float* align_out = gate_out + (size_t)32 * 256;

    convert_mlen<<<1, 32, 0, stream>>>(mlraw, mlen);
    proc_mem<<<8192, 128, 0, stream>>>(enc, W_mem, pm);
    transpose_wq<<<512, 256, 0, stream>>>(W_q, wqT);
    zero_f<<<(zlen + 255) / 256, 256, 0, stream>>>(ws + zs0, zlen);
    repack_mfma<<<(unsigned)((SLAB_A + 255) / 256), 256, 0, stream>>>(
        Wih_a, Whh_a, slabA, 768, NKA, SLAB_A);
    repack_mfma<<<(unsigned)((SLAB_D + 255) / 256), 256, 0, stream>>>(
        Wih_d, Whh_d, slabD, 1536, NKD, SLAB_D);

    P pv;
    pv.slabA = slabA; pv.slabD = slabD;
    pv.XAb0 = XAb0; pv.XAb1 = XAb0 + XA_SZ;
    pv.XDb0 = XAb0 + 2 * XA_SZ; pv.XDb1 = XAb0 + 2 * XA_SZ + XD_SZ;
    pv.bA = b_a; pv.bD = b_d;
    pv.hA0 = hA0; pv.hA1 = hA1; pv.cA = cA;
    pv.hD0 = hD0; pv.hD1 = hD1; pv.cD = cD;
    pv.enc = enc; pv.pm = pm; pv.wqT = wqT;
    pv.Wlc = Wlc; pv.Wld = Wld; pv.vatt = v_att;
    pv.Wp = W_proj; pv.bp = b_proj; pv.Wg = W_gate; pv.bg = b_gate;
    pv.inputs = inputs; pv.Wpre1 = W_pre1; pv.Wpre2 = W_pre2;
    pv.aw = aw; pv.cum = cum; pv.ctx0 = ctx0; pv.ctx1 = ctx1;
    pv.mlen = mlen;
    pv.mel = mel_out; pv.gate = gate_out; pv.align = align_out;
    pv.bar = bar;

    void* args[] = { &pv };
    hipError_t e = hipLaunchCooperativeKernel((const void*)coop_main,
                                              dim3(NBLK), dim3(256), args, 0, stream);
    if (e != hipSuccess) {
        // fallback: discrete launches of the same phases (R18 behavior)
        fb2<<<96, 256, 0, stream>>>(pv, -2);
        for (int t = -1; t <= 255; ++t) {
            fb1<<<NBLK, 256, 0, stream>>>(pv, t);
            fb2<<<96, 256, 0, stream>>>(pv, t);
        }
    }
}

// Round 20
// 46988.339 us; speedup vs baseline: 1.9193x; 1.9193x over previous
//
#include <hip/hip_runtime.h>
#include <math.h>

#define T_DEC 256
#define NKA 56          // A: K=1792 = 56 k-chunks of 32
#define NKD 80          // D: K=2560 = 80 k-chunks of 32

typedef __attribute__((ext_vector_type(8))) short bf16x8;
typedef __attribute__((ext_vector_type(4))) float f32x4;

__device__ __forceinline__ float sigf(float x) { return 1.0f / (1.0f + __expf(-x)); }
__device__ __forceinline__ float tanhfast(float x) {
    return 1.0f - 2.0f / (__expf(2.0f * x) + 1.0f);
}
__device__ __forceinline__ unsigned short f2u(float f) {   // RNE bf16
    union { float ff; unsigned int i; } v; v.ff = f;
    unsigned int x = v.i;
    return (unsigned short)((x + 0x7FFFu + ((x >> 16) & 1u)) >> 16);
}
// offset of X[b][k] inside a B-frag-ordered X buffer (chunks of 32 k, 2 col-tiles)
__device__ __forceinline__ size_t xoff(int k, int b) {
    int c = k >> 5, kk = k & 31, ct = b >> 4;
    int lane = (b & 15) | ((kk >> 3) << 4);
    int j = kk & 7;
    return ((size_t)(c * 2 + ct) * 64 + lane) * 8 + j;
}

typedef __attribute__((address_space(1))) const void* gas_t;
typedef __attribute__((address_space(3))) void* las_t;
__device__ __forceinline__ void gl_lds16(const void* g, void* l) {
    __builtin_amdgcn_global_load_lds((gas_t)g, (las_t)l, 16, 0, 0);
}

// ---------------- small prologue kernels ----------------
__global__ void convert_mlen(const void* p, int* out) {
    int b = threadIdx.x;
    const int* pi = (const int*)p;
    const float* pf = (const float*)p;
    __shared__ int mode;
    if (b == 0) {
        int i0 = pi[0], i1 = pi[1];
        float f0 = pf[0];
        if (i0 >= 1 && i0 <= 512 && i1 == 0) mode = 2;
        else if (i0 >= 1 && i0 <= 512) mode = 0;
        else if (f0 >= 1.0f && f0 <= 512.0f) mode = 1;
        else mode = 0;
    }
    __syncthreads();
    int v;
    if (mode == 2)      v = pi[2 * b];
    else if (mode == 1) v = (int)(pf[b] + 0.5f);
    else                v = pi[b];
    if (v < 1) v = 1;
    if (v > 256) v = 256;
    out[b] = v;
}

__global__ void zero_f(float* __restrict__ p, int n) {
    int i = blockIdx.x * blockDim.x + threadIdx.x;
    if (i < n) p[i] = 0.0f;
}

__global__ __launch_bounds__(128) void proc_mem(const float* __restrict__ mem,
                                                const float* __restrict__ Wm,
                                                float* __restrict__ pm) {
    int r = blockIdx.x;
    int d = threadIdx.x;
    __shared__ float xs[512];
    for (int k = d; k < 512; k += 128) xs[k] = mem[(size_t)r * 512 + k];
    __syncthreads();
    const float* wr = Wm + (size_t)d * 512;
    float s = 0.f;
    for (int k = 0; k < 512; k += 4) {
        float4 w = *reinterpret_cast<const float4*>(wr + k);
        s = fmaf(xs[k], w.x, s); s = fmaf(xs[k+1], w.y, s);
        s = fmaf(xs[k+2], w.z, s); s = fmaf(xs[k+3], w.w, s);
    }
    pm[(size_t)r * 128 + d] = s;
}

__global__ __launch_bounds__(256) void transpose_wq(const float* __restrict__ Wq,
                                                    float* __restrict__ wqT) {
    int i = blockIdx.x * 256 + threadIdx.x;
    int d = i & 127, k = i >> 7;
    wqT[i] = Wq[(size_t)d * 1024 + k];
}

// repack W into A-fragment lane order (verified R17/R18)
__global__ __launch_bounds__(256) void repack_mfma(const float* __restrict__ Wih,
                                                   const float* __restrict__ Whh,
                                                   unsigned short* __restrict__ slab,
                                                   int KIH, int nK, long total) {
    long idx = (long)blockIdx.x * 256 + threadIdx.x;
    if (idx >= total) return;
    int j = (int)(idx & 7);
    int l = (int)((idx >> 3) & 63);
    long rest = idx >> 9;
    int i = (int)(rest % nK), rt = (int)(rest / nK);
    int x = l & 15;
    int row = (x & 3) * 1024 + rt * 4 + (x >> 2);
    int k = i * 32 + (l >> 4) * 8 + j;
    float v = (k < KIH) ? Wih[(size_t)row * KIH + k]
                        : Whh[(size_t)row * 1024 + (k - KIH)];
    slab[idx] = f2u(v);
}

// ---------------- kgemm_mfma: 8-wave K-split, depth-6 rotation ----------------
template<int NQ>
__device__ __forceinline__ void mfma_part(const unsigned short* __restrict__ ap,
                                          const unsigned short* __restrict__ xp,
                                          f32x4& acc0, f32x4& acc1) {
    bf16x8 ab[6], bb0[6], bb1[6];
    #pragma unroll
    for (int p = 0; p < 6; ++p) {
        if (p < NQ) {
            ab[p]  = *reinterpret_cast<const bf16x8*>(ap + (size_t)p * 512);
            bb0[p] = *reinterpret_cast<const bf16x8*>(xp + (size_t)(2 * p) * 512);
            bb1[p] = *reinterpret_cast<const bf16x8*>(xp + (size_t)(2 * p + 1) * 512);
        }
    }
    #pragma unroll
    for (int i = 0; i < NQ; ++i) {
        const int s = i % 6;
        acc0 = __builtin_amdgcn_mfma_f32_16x16x32_bf16(ab[s], bb0[s], acc0, 0, 0, 0);
        acc1 = __builtin_amdgcn_mfma_f32_16x16x32_bf16(ab[s], bb1[s], acc1, 0, 0, 0);
        if (i + 6 < NQ) {
            ab[s]  = *reinterpret_cast<const bf16x8*>(ap + (size_t)(i + 6) * 512);
            bb0[s] = *reinterpret_cast<const bf16x8*>(xp + (size_t)(2 * (i + 6)) * 512);
            bb1[s] = *reinterpret_cast<const bf16x8*>(xp + (size_t)(2 * (i + 6) + 1) * 512);
        }
    }
}

// 512 blocks x 512 thr (8 waves). Block rt: 16 rows (4 units) x 32 batches;
// wave w owns k-chunks [w*NQ, (w+1)*NQ); LDS-reduce; wave 0 does gates.
__global__ __launch_bounds__(512) void kgemm_mfma(
    const unsigned short* __restrict__ slabA, const unsigned short* __restrict__ slabD,
    const unsigned short* __restrict__ XA, const unsigned short* __restrict__ XD,
    unsigned short* __restrict__ XAn, unsigned short* __restrict__ XDn,
    const float* __restrict__ bA, const float* __restrict__ bD,
    float* __restrict__ hAn, float* __restrict__ cA,
    float* __restrict__ hDn, float* __restrict__ cD,
    int do_a, int do_d)
{
    __shared__ f32x4 red[7][2][64];
    int blk = blockIdx.x;
    bool isA = blk < 256;
    if (isA ? !do_a : !do_d) return;
    int rt = isA ? blk : blk - 256;
    int tid = threadIdx.x;
    int l = tid & 63, w = tid >> 6;       // w = 0..7
    f32x4 acc0 = {0.f, 0.f, 0.f, 0.f}, acc1 = {0.f, 0.f, 0.f, 0.f};
    if (isA) {
        const unsigned short* ap = slabA + ((size_t)(rt * NKA + w * 7) * 64 + l) * 8;
        const unsigned short* xp = XA + ((size_t)(w * 7) * 128 + l) * 8;
        mfma_part<7>(ap, xp, acc0, acc1);
    } else {
        const unsigned short* ap = slabD + ((size_t)(rt * NKD + w * 10) * 64 + l) * 8;
        const unsigned short* xp = XD + ((size_t)(w * 10) * 128 + l) * 8;
        mfma_part<10>(ap, xp, acc0, acc1);
    }
    if (w > 0) { red[w - 1][0][l] = acc0; red[w - 1][1][l] = acc1; }
    __syncthreads();
    if (w != 0) return;
    #pragma unroll
    for (int q = 0; q < 7; ++q) {
        f32x4 r0 = red[q][0][l], r1 = red[q][1][l];
        acc0[0] += r0[0]; acc0[1] += r0[1]; acc0[2] += r0[2]; acc0[3] += r0[3];
        acc1[0] += r1[0]; acc1[1] += r1[1]; acc1[2] += r1[2]; acc1[3] += r1[3];
    }
    // C layout: col = lane&15, row = (lane>>4)*4 + reg -> lane holds all 4 gates
    // of unit u = rt*4 + (l>>4), for batches (l&15) and 16+(l&15).
    int u = rt * 4 + (l >> 4);
    const float* bias = isA ? bA : bD;
    float bi = bias[u], bf = bias[1024 + u], bg = bias[2048 + u], bo = bias[3072 + u];
    float* cio = isA ? cA : cD;
    float* hout = isA ? hAn : hDn;
    #pragma unroll
    for (int ct = 0; ct < 2; ++ct) {
        f32x4 z = ct ? acc1 : acc0;
        int b = ct * 16 + (l & 15);
        int idx = b * 1024 + u;
        float cn = sigf(z[1] + bf) * cio[idx] + sigf(z[0] + bi) * tanhfast(z[2] + bg);
        float hn = sigf(z[3] + bo) * tanhfast(cn);
        cio[idx] = cn;
        hout[idx] = hn;
        unsigned short hb = f2u(hn);
        if (isA) {              // hA(t+1): XA-next k=768+u ; XD-next k=u
            XAn[xoff(768 + u, b)] = hb;
            XDn[xoff(u, b)] = hb;
        } else {                // hD(t): XD-next k=1536+u
            XDn[xoff(1536 + u, b)] = hb;
        }
    }
}

// ---------------- kpa: proj(t) | attn(t+1)+ctx | prenet(t+2) ----------------
struct SHa {
    float wlc0[31][32], wlc1[31][32];
    float wlds[128][36];
    float vs[128];
    float hs[1024];
    float red[256];
    float pqs[128];
    float aw0s[288], aw1s[288];
    float sm[256];
    float red4[4];
};
struct SHp { float hc[1536]; float redp[164]; };
struct SHn { float xs[80]; float h1[256]; };
union SHU { SHa a; SHp p; SHn n; };

__global__ __launch_bounds__(256) void kpa(
    const float* __restrict__ enc, const float* __restrict__ pm,
    const float* __restrict__ wqT,
    const float* __restrict__ Wlc, const float* __restrict__ Wld,
    const float* __restrict__ vatt,
    const float* __restrict__ Wp, const float* __restrict__ bp,
    const float* __restrict__ Wg, const float* __restrict__ bg,
    const float* __restrict__ inputs,
    const float* __restrict__ Wpre1, const float* __restrict__ Wpre2,
    const float* __restrict__ hAnext,   // h_a(t+1)
    const float* __restrict__ hDcur,    // h_d(t)
    const float* __restrict__ ctxc,     // ctx(t)
    float* __restrict__ ctxn,           // ctx(t+1) out
    float* __restrict__ preDst,         // prenet(t+2) out (fp32)
    unsigned short* __restrict__ XAn,   // X_A(t+1) bf16 frag buffer
    unsigned short* __restrict__ XDn,   // X_D(t+1) bf16 frag buffer
    float* __restrict__ aw, float* __restrict__ cum,
    const int* __restrict__ mlen,
    float* __restrict__ mel, float* __restrict__ gate,
    float* __restrict__ align_out, int t)
{
    __shared__ SHU sh;
    const int tid = threadIdx.x;
    const int blk = blockIdx.x;
    if (blk < 32) {
        if (t < 0) return;
        int b = blk;
        for (int k = tid; k < 1024; k += 256) sh.p.hc[k] = hDcur[(size_t)b * 1024 + k];
        for (int k = tid; k < 512; k += 256)  sh.p.hc[1024 + k] = ctxc[(size_t)b * 512 + k];
        __syncthreads();
        if (tid < 162) {
            int o = tid >> 1, hf = tid & 1;
            const float* wr = (o < 80) ? (Wp + (size_t)o * 1536) : Wg;
            float s = 0.f;
            int k0 = hf * 768;
            for (int k = k0; k < k0 + 768; k += 4) {
                float4 w = *reinterpret_cast<const float4*>(wr + k);
                s = fmaf(sh.p.hc[k], w.x, s);   s = fmaf(sh.p.hc[k+1], w.y, s);
                s = fmaf(sh.p.hc[k+2], w.z, s); s = fmaf(sh.p.hc[k+3], w.w, s);
            }
            sh.p.redp[tid] = s;
        }
        __syncthreads();
        if (tid < 81) {
            float s = sh.p.redp[2 * tid] + sh.p.redp[2 * tid + 1];
            if (tid < 80) mel[((size_t)b * T_DEC + t) * 80 + tid] = s + bp[tid];
            else          gate[(size_t)b * T_DEC + t] = s + bg[0];
        }
    } else if (blk < 64) {
        if (t < -1 || t >= 255) return;
        int b = blk - 32, tt = t + 1;
        for (int i = tid; i < 992; i += 256) {
            int k = i >> 5, f = i & 31;
            sh.a.wlc0[k][f] = Wlc[(size_t)f * 62 + k];
            sh.a.wlc1[k][f] = Wlc[(size_t)f * 62 + 31 + k];
        }
        for (int i = tid; i < 4096; i += 256) sh.a.wlds[i >> 5][i & 31] = Wld[i];
        if (tid < 128) sh.a.vs[tid] = vatt[tid];
        for (int k = tid; k < 1024; k += 256) sh.a.hs[k] = hAnext[(size_t)b * 1024 + k];
        for (int i = tid; i < 288; i += 256) {
            int pos = i - 16;
            float v0 = 0.f, v1 = 0.f;
            if (pos >= 0 && pos < 256) {
                v0 = aw[(size_t)b * 256 + pos];
                v1 = cum[(size_t)b * 256 + pos];
            }
            sh.a.aw0s[i] = v0; sh.a.aw1s[i] = v1;
        }
        __syncthreads();
        {
            int d = tid & 127, hf = tid >> 7;
            float s = 0.f;
            int k0 = hf * 512;
            for (int k = k0; k < k0 + 512; ++k)
                s = fmaf(sh.a.hs[k], wqT[(size_t)k * 128 + d], s);
            sh.a.red[tid] = s;
        }
        __syncthreads();
        if (tid < 128) sh.a.pqs[tid] = sh.a.red[tid] + sh.a.red[tid + 128];
        __syncthreads();
        float cf[32];
        #pragma unroll
        for (int f = 0; f < 32; ++f) cf[f] = 0.f;
        for (int k = 0; k < 31; ++k) {
            float a0 = sh.a.aw0s[tid + 1 + k], a1 = sh.a.aw1s[tid + 1 + k];
            #pragma unroll
            for (int fq = 0; fq < 8; ++fq) {
                float4 w0 = *reinterpret_cast<const float4*>(&sh.a.wlc0[k][fq << 2]);
                float4 w1 = *reinterpret_cast<const float4*>(&sh.a.wlc1[k][fq << 2]);
                cf[fq*4+0] = fmaf(a0, w0.x, fmaf(a1, w1.x, cf[fq*4+0]));
                cf[fq*4+1] = fmaf(a0, w0.y, fmaf(a1, w1.y, cf[fq*4+1]));
                cf[fq*4+2] = fmaf(a0, w0.z, fmaf(a1, w1.z, cf[fq*4+2]));
                cf[fq*4+3] = fmaf(a0, w0.w, fmaf(a1, w1.w, cf[fq*4+3]));
            }
        }
        float e = 0.f;
        {
            const float* pmr = pm + ((size_t)b * 256 + tid) * 128;
            for (int d = 0; d < 128; ++d) {
                float loc0 = 0.f, loc1 = 0.f;
                #pragma unroll
                for (int fq = 0; fq < 8; ++fq) {
                    float4 w = *reinterpret_cast<const float4*>(&sh.a.wlds[d][fq << 2]);
                    loc0 = fmaf(cf[fq*4+0], w.x, loc0); loc1 = fmaf(cf[fq*4+1], w.y, loc1);
                    loc0 = fmaf(cf[fq*4+2], w.z, loc0); loc1 = fmaf(cf[fq*4+3], w.w, loc1);
                }
                float a = tanhfast(sh.a.pqs[d] + (loc0 + loc1) + pmr[d]);
                e = fmaf(a, sh.a.vs[d], e);
            }
        }
        if (tid >= mlen[b]) e = -1e9f;
        float m = e;
        #pragma unroll
        for (int o2 = 32; o2 >= 1; o2 >>= 1) m = fmaxf(m, __shfl_xor(m, o2));
        if ((tid & 63) == 0) sh.a.red4[tid >> 6] = m;
        __syncthreads();
        m = fmaxf(fmaxf(sh.a.red4[0], sh.a.red4[1]), fmaxf(sh.a.red4[2], sh.a.red4[3]));
        __syncthreads();
        float pe = __expf(e - m);
        float s = pe;
        #pragma unroll
        for (int o2 = 32; o2 >= 1; o2 >>= 1) s += __shfl_xor(s, o2);
        if ((tid & 63) == 0) sh.a.red4[tid >> 6] = s;
        __syncthreads();
        s = sh.a.red4[0] + sh.a.red4[1] + sh.a.red4[2] + sh.a.red4[3];
        float w = pe / s;
        sh.a.sm[tid] = w;
        aw[(size_t)b * 256 + tid] = w;
        cum[(size_t)b * 256 + tid] += w;
        align_out[((size_t)b * T_DEC + tt) * 256 + tid] = w;
        __syncthreads();
        for (int d = tid; d < 512; d += 256) {
            const float* mb = enc + (size_t)b * 131072 + d;
            float s0 = 0.f, s1 = 0.f, s2 = 0.f, s3 = 0.f;
            #pragma unroll 4
            for (int q2 = 0; q2 < 256; q2 += 4) {
                s0 = fmaf(sh.a.sm[q2],     mb[(size_t)q2 * 512],       s0);
                s1 = fmaf(sh.a.sm[q2 + 1], mb[(size_t)(q2 + 1) * 512], s1);
                s2 = fmaf(sh.a.sm[q2 + 2], mb[(size_t)(q2 + 2) * 512], s2);
                s3 = fmaf(sh.a.sm[q2 + 3], mb[(size_t)(q2 + 3) * 512], s3);
            }
            float sv = (s0 + s1) + (s2 + s3);
            ctxn[(size_t)b * 512 + d] = sv;
            unsigned short cb16 = f2u(sv);
            XAn[xoff(256 + d, b)] = cb16;
            XDn[xoff(1024 + d, b)] = cb16;
        }
    } else if (blk < 96) {
        int ts = t + 2;
        if (ts > 255) return;
        int b = blk - 64;
        if (tid < 80) sh.n.xs[tid] = (ts == 0) ? 0.0f
                        : inputs[((size_t)b * T_DEC + (ts - 1)) * 80 + tid];
        __syncthreads();
        {
            const float* wr = Wpre1 + (size_t)tid * 80;
            float s = 0.f;
            #pragma unroll 8
            for (int k = 0; k < 80; ++k) s = fmaf(sh.n.xs[k], wr[k], s);
            sh.n.h1[tid] = fmaxf(s, 0.0f);
        }
        __syncthreads();
        {
            const float* wr = Wpre2 + (size_t)tid * 256;
            float s = 0.f;
            for (int k = 0; k < 256; k += 4) {
                float4 w = *reinterpret_cast<const float4*>(wr + k);
                s = fmaf(sh.n.h1[k], w.x, s);   s = fmaf(sh.n.h1[k+1], w.y, s);
                s = fmaf(sh.n.h1[k+2], w.z, s); s = fmaf(sh.n.h1[k+3], w.w, s);
            }
            float v = fmaxf(s, 0.0f);
            preDst[(size_t)b * 256 + tid] = v;
            XAn[xoff(tid, b)] = f2u(v);       // pre region of X_A(ts-1)
        }
    }
}

// ---------------- host ----------------
extern "C" void kernel_launch(void* const* d_in, const int* in_sizes, int n_in,
                              void* d_out, int out_size, void* d_ws, size_t ws_size,
                              hipStream_t stream) {
    const float* enc    = (const float*)d_in[0];
    const float* inputs = (const float*)d_in[1];
    const void*  mlraw  = d_in[2];
    const float* W_pre1 = (const float*)d_in[3];
    const float* W_pre2 = (const float*)d_in[4];
    const float* Wih_a  = (const float*)d_in[5];
    const float* Whh_a  = (const float*)d_in[6];
    const float* b_a    = (const float*)d_in[7];
    const float* W_q    = (const float*)d_in[8];
    const float* W_mem  = (const float*)d_in[9];
    const float* Wlc    = (const float*)d_in[10];
    const float* Wld    = (const float*)d_in[11];
    const float* v_att  = (const float*)d_in[12];
    const float* Wih_d  = (const float*)d_in[13];
    const float* Whh_d  = (const float*)d_in[14];
    const float* b_d    = (const float*)d_in[15];
    const float* W_proj = (const float*)d_in[16];
    const float* b_proj = (const float*)d_in[17];
    const float* W_gate = (const float*)d_in[18];
    const float* b_gate = (const float*)d_in[19];

    const long SLAB_A = (long)256 * NKA * 512;    // 7,340,032 ushorts
    const long SLAB_D = (long)256 * NKD * 512;    // 10,485,760 ushorts
    const long XA_SZ  = (long)NKA * 2 * 512;      // 57,344 ushorts
    const long XD_SZ  = (long)NKD * 2 * 512;      // 81,920 ushorts

    float* ws = (float*)d_ws;
    size_t o = 0;
    float* pm    = ws + o; o += 1048576;
    float* wqT   = ws + o; o += 131072;
    float* preB0 = ws + o; o += 8192;
    float* preB1 = ws + o; o += 8192;
    size_t zs0 = o;
    float* hA0 = ws + o; o += 32768;
    float* hA1 = ws + o; o += 32768;
    float* cA  = ws + o; o += 32768;
    float* hD0 = ws + o; o += 32768;
    float* hD1 = ws + o; o += 32768;
    float* cD  = ws + o; o += 32768;
    float* aw  = ws + o; o += 8192;
    float* cum = ws + o; o += 8192;
    float* ctx0 = ws + o; o += 16384;
    float* ctx1 = ws + o; o += 16384;
    unsigned short* XAb0 = (unsigned short*)(ws + o);
    o += (size_t)(2 * XA_SZ + 2 * XD_SZ + 1) / 2;   // 139,264 floats
    int zlen = (int)(o - zs0);
    int* mlen = (int*)(ws + o); o += 32;
    unsigned short* slabA = (unsigned short*)(ws + o);
    unsigned short* slabD = slabA + SLAB_A;
    size_t full_fl = o + (size_t)(SLAB_A + SLAB_D + 1) / 2;
    if (ws_size < full_fl * 4) return;   // diagnostic: 0.1455 signature

    unsigned short* XAb[2] = { XAb0, XAb0 + XA_SZ };
    unsigned short* XDb[2] = { XAb0 + 2 * XA_SZ, XAb0 + 2 * XA_SZ + XD_SZ };

    float* out       = (float*)d_out;
    float* mel_out   = out;
    float* gate_out  = out + (size_t)32 * 256 * 80;
    float* align_out = gate_out + (size_t)32 * 256;

    convert_mlen<<<1, 32, 0, stream>>>(mlraw, mlen);
    proc_mem<<<8192, 128, 0, stream>>>(enc, W_mem, pm);
    transpose_wq<<<512, 256, 0, stream>>>(W_q, wqT);
    zero_f<<<(zlen + 255) / 256, 256, 0, stream>>>(ws + zs0, zlen);
    repack_mfma<<<(unsigned)((SLAB_A + 255) / 256), 256, 0, stream>>>(
        Wih_a, Whh_a, slabA, 768, NKA, SLAB_A);
    repack_mfma<<<(unsigned)((SLAB_D + 255) / 256), 256, 0, stream>>>(
        Wih_d, Whh_d, slabD, 1536, NKD, SLAB_D);

    float* hA[2] = { hA0, hA1 };
    float* hD[2] = { hD0, hD1 };
    float* ctxP[2] = { ctx0, ctx1 };
    float* preB[2] = { preB0, preB1 };

    // prenet(0) -> pre region of X_A(-1) (parity 1)
    kpa<<<96, 256, 0, stream>>>(enc, pm, wqT, Wlc, Wld, v_att,
                                W_proj, b_proj, W_gate, b_gate,
                                inputs, W_pre1, W_pre2,
                                hA0, hD0, ctx0, ctx1, preB[0],
                                XAb[1], XDb[1],
                                aw, cum, mlen, mel_out, gate_out, align_out, -2);
    for (int t = -1; t <= 255; ++t) {
        int pc = t & 1, pn = (t + 1) & 1;
        int do_a = (t < 255), do_d = (t >= 0);
        kgemm_mfma<<<512, 512, 0, stream>>>(
            slabA, slabD, XAb[pc], XDb[pc], XAb[pn], XDb[pn],
            b_a, b_d, hA[pn], cA, hD[pc], cD, do_a, do_d);
        kpa<<<96, 256, 0, stream>>>(enc, pm, wqT, Wlc, Wld, v_att,
                                    W_proj, b_proj, W_gate, b_gate,
                                    inputs, W_pre1, W_pre2,
                                    hA[pn], hD[pc], ctxP[pc], ctxP[pn], preB[pc],
                                    XAb[pn], XDb[pn],
                                    aw, cum, mlen, mel_out, gate_out, align_out, t);
    }
}

// Round 21
// 29748.315 us; speedup vs baseline: 3.0316x; 1.5795x over previous
//
#include <hip/hip_runtime.h>
#include <math.h>

#define T_DEC 256
#define NKA 56          // A: K=1792 = 56 k-chunks of 32
#define NKD 80          // D: K=2560 = 80 k-chunks of 32

typedef __attribute__((ext_vector_type(8))) short bf16x8;
typedef __attribute__((ext_vector_type(4))) float f32x4;

__device__ __forceinline__ float sigf(float x) { return 1.0f / (1.0f + __expf(-x)); }
__device__ __forceinline__ float tanhfast(float x) {
    return 1.0f - 2.0f / (__expf(2.0f * x) + 1.0f);
}
__device__ __forceinline__ unsigned short f2u(float f) {   // RNE bf16
    union { float ff; unsigned int i; } v; v.ff = f;
    unsigned int x = v.i;
    return (unsigned short)((x + 0x7FFFu + ((x >> 16) & 1u)) >> 16);
}
// offset of X[b][k] inside a B-frag-ordered X buffer
__device__ __forceinline__ size_t xoff(int k, int b) {
    int c = k >> 5, kk = k & 31, ct = b >> 4;
    int lane = (b & 15) | ((kk >> 3) << 4);
    int j = kk & 7;
    return ((size_t)(c * 2 + ct) * 64 + lane) * 8 + j;
}

// ---------------- prologue kernels (verified) ----------------
__global__ void convert_mlen(const void* p, int* out) {
    int b = threadIdx.x;
    const int* pi = (const int*)p;
    const float* pf = (const float*)p;
    __shared__ int mode;
    if (b == 0) {
        int i0 = pi[0], i1 = pi[1];
        float f0 = pf[0];
        if (i0 >= 1 && i0 <= 512 && i1 == 0) mode = 2;
        else if (i0 >= 1 && i0 <= 512) mode = 0;
        else if (f0 >= 1.0f && f0 <= 512.0f) mode = 1;
        else mode = 0;
    }
    __syncthreads();
    int v;
    if (mode == 2)      v = pi[2 * b];
    else if (mode == 1) v = (int)(pf[b] + 0.5f);
    else                v = pi[b];
    if (v < 1) v = 1;
    if (v > 256) v = 256;
    out[b] = v;
}

__global__ void zero_f(float* __restrict__ p, int n) {
    int i = blockIdx.x * blockDim.x + threadIdx.x;
    if (i < n) p[i] = 0.0f;
}

__global__ __launch_bounds__(128) void proc_mem(const float* __restrict__ mem,
                                                const float* __restrict__ Wm,
                                                float* __restrict__ pm) {
    int r = blockIdx.x;
    int d = threadIdx.x;
    __shared__ float xs[512];
    for (int k = d; k < 512; k += 128) xs[k] = mem[(size_t)r * 512 + k];
    __syncthreads();
    const float* wr = Wm + (size_t)d * 512;
    float s = 0.f;
    for (int k = 0; k < 512; k += 4) {
        float4 w = *reinterpret_cast<const float4*>(wr + k);
        s = fmaf(xs[k], w.x, s); s = fmaf(xs[k+1], w.y, s);
        s = fmaf(xs[k+2], w.z, s); s = fmaf(xs[k+3], w.w, s);
    }
    pm[(size_t)r * 128 + d] = s;
}

__global__ __launch_bounds__(256) void transpose_wq(const float* __restrict__ Wq,
                                                    float* __restrict__ wqT) {
    int i = blockIdx.x * 256 + threadIdx.x;
    int d = i & 127, k = i >> 7;
    wqT[i] = Wq[(size_t)d * 1024 + k];
}

__global__ __launch_bounds__(256) void repack_mfma(const float* __restrict__ Wih,
                                                   const float* __restrict__ Whh,
                                                   unsigned short* __restrict__ slab,
                                                   int KIH, int nK, long total) {
    long idx = (long)blockIdx.x * 256 + threadIdx.x;
    if (idx >= total) return;
    int j = (int)(idx & 7);
    int l = (int)((idx >> 3) & 63);
    long rest = idx >> 9;
    int i = (int)(rest % nK), rt = (int)(rest / nK);
    int x = l & 15;
    int row = (x & 3) * 1024 + rt * 4 + (x >> 2);
    int k = i * 32 + (l >> 4) * 8 + j;
    float v = (k < KIH) ? Wih[(size_t)row * KIH + k]
                        : Whh[(size_t)row * 1024 + (k - KIH)];
    slab[idx] = f2u(v);
}

// ---------------- 8-wave MFMA GEMM core (verified R20) ----------------
template<int NQ>
__device__ __forceinline__ void mfma_part(const unsigned short* __restrict__ ap,
                                          const unsigned short* __restrict__ xp,
                                          f32x4& acc0, f32x4& acc1) {
    bf16x8 ab[6], bb0[6], bb1[6];
    #pragma unroll
    for (int p = 0; p < 6; ++p) {
        if (p < NQ) {
            ab[p]  = *reinterpret_cast<const bf16x8*>(ap + (size_t)p * 512);
            bb0[p] = *reinterpret_cast<const bf16x8*>(xp + (size_t)(2 * p) * 512);
            bb1[p] = *reinterpret_cast<const bf16x8*>(xp + (size_t)(2 * p + 1) * 512);
        }
    }
    #pragma unroll
    for (int i = 0; i < NQ; ++i) {
        const int s = i % 6;
        acc0 = __builtin_amdgcn_mfma_f32_16x16x32_bf16(ab[s], bb0[s], acc0, 0, 0, 0);
        acc1 = __builtin_amdgcn_mfma_f32_16x16x32_bf16(ab[s], bb1[s], acc1, 0, 0, 0);
        if (i + 6 < NQ) {
            ab[s]  = *reinterpret_cast<const bf16x8*>(ap + (size_t)(i + 6) * 512);
            bb0[s] = *reinterpret_cast<const bf16x8*>(xp + (size_t)(2 * (i + 6)) * 512);
            bb1[s] = *reinterpret_cast<const bf16x8*>(xp + (size_t)(2 * (i + 6) + 1) * 512);
        }
    }
}

// GEMM block body: 512 thr, wave w owns k-chunks [w*NQ,(w+1)*NQ)
template<int NQ>
__device__ void gemm_body(f32x4 (*red)[2][64],
                          const unsigned short* __restrict__ slab,
                          const unsigned short* __restrict__ X,
                          unsigned short* __restrict__ XAn,
                          unsigned short* __restrict__ XDn,
                          const float* __restrict__ bias,
                          float* __restrict__ hout, float* __restrict__ cio,
                          int rt, bool isA) {
    int tid = threadIdx.x;
    int l = tid & 63, w = tid >> 6;
    f32x4 acc0 = {0.f,0.f,0.f,0.f}, acc1 = {0.f,0.f,0.f,0.f};
    {
        const int NK = isA ? NKA : NKD;
        const unsigned short* ap = slab + ((size_t)(rt * NK + w * NQ) * 64 + l) * 8;
        const unsigned short* xp = X + ((size_t)(w * NQ) * 128 + l) * 8;
        mfma_part<NQ>(ap, xp, acc0, acc1);
    }
    if (w > 0) { red[w - 1][0][l] = acc0; red[w - 1][1][l] = acc1; }
    __syncthreads();
    if (w != 0) return;
    #pragma unroll
    for (int q = 0; q < 7; ++q) {
        f32x4 r0 = red[q][0][l], r1 = red[q][1][l];
        acc0[0] += r0[0]; acc0[1] += r0[1]; acc0[2] += r0[2]; acc0[3] += r0[3];
        acc1[0] += r1[0]; acc1[1] += r1[1]; acc1[2] += r1[2]; acc1[3] += r1[3];
    }
    int u = rt * 4 + (l >> 4);
    float bi = bias[u], bf = bias[1024 + u], bg = bias[2048 + u], bo = bias[3072 + u];
    #pragma unroll
    for (int ct = 0; ct < 2; ++ct) {
        f32x4 z = ct ? acc1 : acc0;
        int b = ct * 16 + (l & 15);
        int idx = b * 1024 + u;
        float cn = sigf(z[1] + bf) * cio[idx] + sigf(z[0] + bi) * tanhfast(z[2] + bg);
        float hn = sigf(z[3] + bo) * tanhfast(cn);
        cio[idx] = cn;
        hout[idx] = hn;
        unsigned short hb = f2u(hn);
        if (isA) {              // hA(t+1) -> XA(t+1) k=768+u ; XD(t+1) k=u
            XAn[xoff(768 + u, b)] = hb;
            XDn[xoff(u, b)] = hb;
        } else {                // hD(t) -> XD(t+1) k=1536+u
            XDn[xoff(1536 + u, b)] = hb;
        }
    }
}

// ---------------- K1: A-GEMM(t) + proj(t-1) ----------------
struct SH1 {
    union {
        f32x4 red[7][2][64];
        struct { float hc[1536]; float redp[164]; } p;
    } u;
};

__global__ __launch_bounds__(512) void kA(
    const unsigned short* __restrict__ slabA,
    const unsigned short* __restrict__ XA,     // XA(pc)
    unsigned short* __restrict__ XAn,          // XA(pn)
    unsigned short* __restrict__ XDn,          // XD(pn)
    const float* __restrict__ bA,
    float* __restrict__ hAn, float* __restrict__ cA,   // hA(pn)
    const float* __restrict__ hDrd,            // hD(pn) = hD(t-1)
    const float* __restrict__ ctxrd,           // ctx(pn) = ctx(t-1)
    const float* __restrict__ Wp, const float* __restrict__ bp,
    const float* __restrict__ Wg, const float* __restrict__ bg,
    float* __restrict__ mel, float* __restrict__ gate, int t)
{
    __shared__ SH1 sh;
    const int blk = blockIdx.x;
    const int tid = threadIdx.x;
    if (blk < 256) {
        if (t >= 255) return;
        gemm_body<7>(sh.u.red, slabA, XA, XAn, XDn, bA, hAn, cA, blk, true);
    } else {
        int tp = t - 1;
        if (tp < 0) return;
        int b = blk - 256;
        for (int k = tid; k < 1024; k += 512) sh.u.p.hc[k] = hDrd[(size_t)b * 1024 + k];
        for (int k = tid; k < 512; k += 512)  sh.u.p.hc[1024 + k] = ctxrd[(size_t)b * 512 + k];
        __syncthreads();
        if (tid < 162) {
            int o = tid >> 1, hf = tid & 1;
            const float* wr = (o < 80) ? (Wp + (size_t)o * 1536) : Wg;
            float s = 0.f;
            int k0 = hf * 768;
            for (int k = k0; k < k0 + 768; k += 4) {
                float4 w = *reinterpret_cast<const float4*>(wr + k);
                s = fmaf(sh.u.p.hc[k], w.x, s);   s = fmaf(sh.u.p.hc[k+1], w.y, s);
                s = fmaf(sh.u.p.hc[k+2], w.z, s); s = fmaf(sh.u.p.hc[k+3], w.w, s);
            }
            sh.u.p.redp[tid] = s;
        }
        __syncthreads();
        if (tid < 81) {
            float s = sh.u.p.redp[2 * tid] + sh.u.p.redp[2 * tid + 1];
            if (tid < 80) mel[((size_t)b * T_DEC + tp) * 80 + tid] = s + bp[tid];
            else          gate[(size_t)b * T_DEC + tp] = s + bg[0];
        }
    }
}

// ---------------- K2: D-GEMM(t) + attn(t+1) + prenet(t+2) ----------------
struct SH2 {
    union {
        f32x4 red[7][2][64];
        struct {
            float wlc0[31][32], wlc1[31][32];
            float wlds[128][36];
            float vs[128];
            float hs[1024];
            float redq[512];
            float pqs[128];
            float aw0s[288], aw1s[288];
            float sm[256];
            float red8[8];
        } a;
        struct { float xs[80]; float h1[256]; } n;
    } u;
};

__global__ __launch_bounds__(512) void kD(
    const unsigned short* __restrict__ slabD,
    const unsigned short* __restrict__ XD,     // XD(pc)
    unsigned short* __restrict__ XAn,          // XA(pn)
    unsigned short* __restrict__ XDn,          // XD(pn)
    const float* __restrict__ bD,
    float* __restrict__ hDn, float* __restrict__ cD,   // hD(pc) = hD(t)
    const float* __restrict__ hArd,            // hA(pn) = hA(t+1)
    float* __restrict__ ctxn,                  // ctx(pn) = ctx(t+1)
    const float* __restrict__ enc, const float* __restrict__ pm,
    const float* __restrict__ wqT,
    const float* __restrict__ Wlc, const float* __restrict__ Wld,
    const float* __restrict__ vatt,
    const float* __restrict__ inputs,
    const float* __restrict__ Wpre1, const float* __restrict__ Wpre2,
    float* __restrict__ aw, float* __restrict__ cum,
    const int* __restrict__ mlen,
    float* __restrict__ align_out, int t)
{
    __shared__ SH2 sh;
    const int blk = blockIdx.x;
    const int tid = threadIdx.x;
    if (blk < 256) {
        if (t < 0) return;
        gemm_body<10>(sh.u.red, slabD, XD, XAn, XDn, bD, hDn, cD, blk, false);
    } else if (blk < 288) {
        // ---- attn(t+1) (512-thread version of verified R20 body) ----
        if (t < -1 || t >= 255) return;
        int b = blk - 256, tt = t + 1;
        for (int i = tid; i < 992; i += 512) {
            int k = i >> 5, f = i & 31;
            sh.u.a.wlc0[k][f] = Wlc[(size_t)f * 62 + k];
            sh.u.a.wlc1[k][f] = Wlc[(size_t)f * 62 + 31 + k];
        }
        for (int i = tid; i < 4096; i += 512) sh.u.a.wlds[i >> 5][i & 31] = Wld[i];
        if (tid < 128) sh.u.a.vs[tid] = vatt[tid];
        for (int k = tid; k < 1024; k += 512) sh.u.a.hs[k] = hArd[(size_t)b * 1024 + k];
        for (int i = tid; i < 288; i += 512) {
            int pos = i - 16;
            float v0 = 0.f, v1 = 0.f;
            if (pos >= 0 && pos < 256) {
                v0 = aw[(size_t)b * 256 + pos];
                v1 = cum[(size_t)b * 256 + pos];
            }
            sh.u.a.aw0s[i] = v0; sh.u.a.aw1s[i] = v1;
        }
        __syncthreads();
        {   // pq: 4-way k-split
            int d = tid & 127, hf = tid >> 7;    // hf 0..3
            float s = 0.f;
            int k0 = hf * 256;
            for (int k = k0; k < k0 + 256; ++k)
                s = fmaf(sh.u.a.hs[k], wqT[(size_t)k * 128 + d], s);
            sh.u.a.redq[tid] = s;
        }
        __syncthreads();
        if (tid < 128) sh.u.a.pqs[tid] = (sh.u.a.redq[tid] + sh.u.a.redq[tid + 128])
                                       + (sh.u.a.redq[tid + 256] + sh.u.a.redq[tid + 384]);
        __syncthreads();
        float e = -1e30f;
        if (tid < 256) {
            float cf[32];
            #pragma unroll
            for (int f = 0; f < 32; ++f) cf[f] = 0.f;
            for (int k = 0; k < 31; ++k) {
                float a0 = sh.u.a.aw0s[tid + 1 + k], a1 = sh.u.a.aw1s[tid + 1 + k];
                #pragma unroll
                for (int fq = 0; fq < 8; ++fq) {
                    float4 w0 = *reinterpret_cast<const float4*>(&sh.u.a.wlc0[k][fq << 2]);
                    float4 w1 = *reinterpret_cast<const float4*>(&sh.u.a.wlc1[k][fq << 2]);
                    cf[fq*4+0] = fmaf(a0, w0.x, fmaf(a1, w1.x, cf[fq*4+0]));
                    cf[fq*4+1] = fmaf(a0, w0.y, fmaf(a1, w1.y, cf[fq*4+1]));
                    cf[fq*4+2] = fmaf(a0, w0.z, fmaf(a1, w1.z, cf[fq*4+2]));
                    cf[fq*4+3] = fmaf(a0, w0.w, fmaf(a1, w1.w, cf[fq*4+3]));
                }
            }
            e = 0.f;
            const float* pmr = pm + ((size_t)b * 256 + tid) * 128;
            for (int d = 0; d < 128; ++d) {
                float loc0 = 0.f, loc1 = 0.f;
                #pragma unroll
                for (int fq = 0; fq < 8; ++fq) {
                    float4 w = *reinterpret_cast<const float4*>(&sh.u.a.wlds[d][fq << 2]);
                    loc0 = fmaf(cf[fq*4+0], w.x, loc0); loc1 = fmaf(cf[fq*4+1], w.y, loc1);
                    loc0 = fmaf(cf[fq*4+2], w.z, loc0); loc1 = fmaf(cf[fq*4+3], w.w, loc1);
                }
                float a = tanhfast(sh.u.a.pqs[d] + (loc0 + loc1) + pmr[d]);
                e = fmaf(a, sh.u.a.vs[d], e);
            }
            if (tid >= mlen[b]) e = -1e9f;
        }
        float m = e;
        #pragma unroll
        for (int o2 = 32; o2 >= 1; o2 >>= 1) m = fmaxf(m, __shfl_xor(m, o2));
        if ((tid & 63) == 0) sh.u.a.red8[tid >> 6] = m;
        __syncthreads();
        m = fmaxf(fmaxf(fmaxf(sh.u.a.red8[0], sh.u.a.red8[1]),
                        fmaxf(sh.u.a.red8[2], sh.u.a.red8[3])),
                  fmaxf(fmaxf(sh.u.a.red8[4], sh.u.a.red8[5]),
                        fmaxf(sh.u.a.red8[6], sh.u.a.red8[7])));
        __syncthreads();
        float pe = (tid < 256) ? __expf(e - m) : 0.f;
        float s = pe;
        #pragma unroll
        for (int o2 = 32; o2 >= 1; o2 >>= 1) s += __shfl_xor(s, o2);
        if ((tid & 63) == 0) sh.u.a.red8[tid >> 6] = s;
        __syncthreads();
        s = ((sh.u.a.red8[0] + sh.u.a.red8[1]) + (sh.u.a.red8[2] + sh.u.a.red8[3]))
          + ((sh.u.a.red8[4] + sh.u.a.red8[5]) + (sh.u.a.red8[6] + sh.u.a.red8[7]));
        float w = pe / s;
        if (tid < 256) {
            sh.u.a.sm[tid] = w;
            aw[(size_t)b * 256 + tid] = w;
            cum[(size_t)b * 256 + tid] += w;
            align_out[((size_t)b * T_DEC + tt) * 256 + tid] = w;
        }
        __syncthreads();
        {   // ctx: one d per thread
            int d = tid;   // 0..511
            const float* mb = enc + (size_t)b * 131072 + d;
            float s0 = 0.f, s1 = 0.f, s2 = 0.f, s3 = 0.f;
            #pragma unroll 4
            for (int q2 = 0; q2 < 256; q2 += 4) {
                s0 = fmaf(sh.u.a.sm[q2],     mb[(size_t)q2 * 512],       s0);
                s1 = fmaf(sh.u.a.sm[q2 + 1], mb[(size_t)(q2 + 1) * 512], s1);
                s2 = fmaf(sh.u.a.sm[q2 + 2], mb[(size_t)(q2 + 2) * 512], s2);
                s3 = fmaf(sh.u.a.sm[q2 + 3], mb[(size_t)(q2 + 3) * 512], s3);
            }
            float sv = (s0 + s1) + (s2 + s3);
            ctxn[(size_t)b * 512 + d] = sv;
            unsigned short cb16 = f2u(sv);
            XAn[xoff(256 + d, b)] = cb16;
            XDn[xoff(1024 + d, b)] = cb16;
        }
    } else {
        // ---- prenet(t+2) ----
        int ts = t + 2;
        if (ts > 255) return;
        int b = blk - 288;
        if (tid < 80) sh.u.n.xs[tid] = (ts == 0) ? 0.0f
                        : inputs[((size_t)b * T_DEC + (ts - 1)) * 80 + tid];
        __syncthreads();
        if (tid < 256) {
            const float* wr = Wpre1 + (size_t)tid * 80;
            float s = 0.f;
            #pragma unroll 8
            for (int k = 0; k < 80; ++k) s = fmaf(sh.u.n.xs[k], wr[k], s);
            sh.u.n.h1[tid] = fmaxf(s, 0.0f);
        }
        __syncthreads();
        if (tid < 256) {
            const float* wr = Wpre2 + (size_t)tid * 256;
            float s = 0.f;
            for (int k = 0; k < 256; k += 4) {
                float4 w = *reinterpret_cast<const float4*>(wr + k);
                s = fmaf(sh.u.n.h1[k], w.x, s);   s = fmaf(sh.u.n.h1[k+1], w.y, s);
                s = fmaf(sh.u.n.h1[k+2], w.z, s); s = fmaf(sh.u.n.h1[k+3], w.w, s);
            }
            XAn[xoff(tid, b)] = f2u(fmaxf(s, 0.0f));
        }
    }
}

// ---------------- host ----------------
extern "C" void kernel_launch(void* const* d_in, const int* in_sizes, int n_in,
                              void* d_out, int out_size, void* d_ws, size_t ws_size,
                              hipStream_t stream) {
    const float* enc    = (const float*)d_in[0];
    const float* inputs = (const float*)d_in[1];
    const void*  mlraw  = d_in[2];
    const float* W_pre1 = (const float*)d_in[3];
    const float* W_pre2 = (const float*)d_in[4];
    const float* Wih_a  = (const float*)d_in[5];
    const float* Whh_a  = (const float*)d_in[6];
    const float* b_a    = (const float*)d_in[7];
    const float* W_q    = (const float*)d_in[8];
    const float* W_mem  = (const float*)d_in[9];
    const float* Wlc    = (const float*)d_in[10];
    const float* Wld    = (const float*)d_in[11];
    const float* v_att  = (const float*)d_in[12];
    const float* Wih_d  = (const float*)d_in[13];
    const float* Whh_d  = (const float*)d_in[14];
    const float* b_d    = (const float*)d_in[15];
    const float* W_proj = (const float*)d_in[16];
    const float* b_proj = (const float*)d_in[17];
    const float* W_gate = (const float*)d_in[18];
    const float* b_gate = (const float*)d_in[19];

    const long SLAB_A = (long)256 * NKA * 512;    // 7,340,032 ushorts
    const long SLAB_D = (long)256 * NKD * 512;    // 10,485,760 ushorts
    const long XA_SZ  = (long)NKA * 2 * 512;      // 57,344 ushorts
    const long XD_SZ  = (long)NKD * 2 * 512;      // 81,920 ushorts

    float* ws = (float*)d_ws;
    size_t o = 0;
    float* pm  = ws + o; o += 1048576;
    float* wqT = ws + o; o += 131072;
    size_t zs0 = o;
    float* hA0 = ws + o; o += 32768;
    float* hA1 = ws + o; o += 32768;
    float* cA  = ws + o; o += 32768;
    float* hD0 = ws + o; o += 32768;
    float* hD1 = ws + o; o += 32768;
    float* cD  = ws + o; o += 32768;
    float* aw  = ws + o; o += 8192;
    float* cum = ws + o; o += 8192;
    float* ctx0 = ws + o; o += 16384;
    float* ctx1 = ws + o; o += 16384;
    unsigned short* XAb0 = (unsigned short*)(ws + o);
    o += (size_t)(2 * XA_SZ + 2 * XD_SZ + 1) / 2;   // 139,264 floats
    int zlen = (int)(o - zs0);
    int* mlen = (int*)(ws + o); o += 32;
    unsigned short* slabA = (unsigned short*)(ws + o);
    unsigned short* slabD = slabA + SLAB_A;
    size_t full_fl = o + (size_t)(SLAB_A + SLAB_D + 1) / 2;
    if (ws_size < full_fl * 4) return;   // diagnostic: 0.1455 signature

    unsigned short* XAb[2] = { XAb0, XAb0 + XA_SZ };
    unsigned short* XDb[2] = { XAb0 + 2 * XA_SZ, XAb0 + 2 * XA_SZ + XD_SZ };
    float* hA[2] = { hA0, hA1 };
    float* hD[2] = { hD0, hD1 };
    float* ctxP[2] = { ctx0, ctx1 };

    float* out       = (float*)d_out;
    float* mel_out   = out;
    float* gate_out  = out + (size_t)32 * 256 * 80;
    float* align_out = gate_out + (size_t)32 * 256;

    convert_mlen<<<1, 32, 0, stream>>>(mlraw, mlen);
    proc_mem<<<8192, 128, 0, stream>>>(enc, W_mem, pm);
    transpose_wq<<<512, 256, 0, stream>>>(W_q, wqT);
    zero_f<<<(zlen + 255) / 256, 256, 0, stream>>>(ws + zs0, zlen);
    repack_mfma<<<(unsigned)((SLAB_A + 255) / 256), 256, 0, stream>>>(
        Wih_a, Whh_a, slabA, 768, NKA, SLAB_A);
    repack_mfma<<<(unsigned)((SLAB_D + 255) / 256), 256, 0, stream>>>(
        Wih_d, Whh_d, slabD, 1536, NKD, SLAB_D);

    // prenet(0) via kD(t=-2): D skip, attn skip, prenet(0) -> XA(parity 1)
    {
        int t = -2, pc = t & 1, pn = (t + 1) & 1;
        kD<<<320, 512, 0, stream>>>(slabD, XDb[pc], XAb[pn], XDb[pn], b_d,
                                    hD[pc], cD, hA[pn], ctxP[pn],
                                    enc, pm, wqT, Wlc, Wld, v_att,
                                    inputs, W_pre1, W_pre2,
                                    aw, cum, mlen, align_out, t);
    }
    for (int t = -1; t <= 256; ++t) {
        int pc = t & 1, pn = (t + 1) & 1;
        kA<<<288, 512, 0, stream>>>(slabA, XAb[pc], XAb[pn], XDb[pn], b_a,
                                    hA[pn], cA,
                                    hD[pn], ctxP[pn],
                                    W_proj, b_proj, W_gate, b_gate,
                                    mel_out, gate_out, t);
        if (t <= 255)
            kD<<<320, 512, 0, stream>>>(slabD, XDb[pc], XAb[pn], XDb[pn], b_d,
                                        hD[pc], cD, hA[pn], ctxP[pn],
                                        enc, pm, wqT, Wlc, Wld, v_att,
                                        inputs, W_pre1, W_pre2,
                                        aw, cum, mlen, align_out, t);
    }
}